// Round 10
// baseline (1516.026 us; speedup 1.0000x reference)
//
#include <hip/hip_runtime.h>
#include <hip/hip_fp16.h>

#define N_NODES 50000
#define N_EDGES 800000
#define CH 128
#define OUT_CH 64
#define K_ORD 25
#define SLICE ((size_t)N_NODES * CH)   // elements per T_k slice

typedef __attribute__((ext_vector_type(8))) short s16x8;
typedef __attribute__((ext_vector_type(4))) float f32x4;

union U4H8 { uint4 u; __half2 h2[4]; ushort us[8]; };

// ---------- CSR build ----------
__global__ void count_kernel(const int* __restrict__ ei, int* __restrict__ deg_i,
                             int* __restrict__ indeg, int E) {
    int e = blockIdx.x * blockDim.x + threadIdx.x;
    if (e >= E) return;
    int s = ei[e];
    int d = ei[E + e];
    atomicAdd(&deg_i[s], 1);
    atomicAdd(&indeg[d], 1);
}

__global__ __launch_bounds__(256) void scan1_kernel(const int* __restrict__ indeg,
                                                    int* __restrict__ loc,
                                                    int* __restrict__ bsum, int n) {
    __shared__ int tmp[256];
    int tid = threadIdx.x;
    int i = blockIdx.x * 256 + tid;
    int v = (i < n) ? indeg[i] : 0;
    tmp[tid] = v;
    __syncthreads();
    for (int off = 1; off < 256; off <<= 1) {
        int t = (tid >= off) ? tmp[tid - off] : 0;
        __syncthreads();
        tmp[tid] += t;
        __syncthreads();
    }
    if (i < n) loc[i] = tmp[tid] - v;
    if (tid == 255) bsum[blockIdx.x] = tmp[255];
}

__global__ __launch_bounds__(256) void scan2_kernel(int* __restrict__ bsum, int nb) {
    __shared__ int tmp[256];
    int tid = threadIdx.x;
    int v = (tid < nb) ? bsum[tid] : 0;
    tmp[tid] = v;
    __syncthreads();
    for (int off = 1; off < 256; off <<= 1) {
        int t = (tid >= off) ? tmp[tid - off] : 0;
        __syncthreads();
        tmp[tid] += t;
        __syncthreads();
    }
    if (tid < nb) bsum[tid] = tmp[tid] - v;
    if (tid == 255) bsum[nb] = tmp[255];
}

__global__ __launch_bounds__(256) void scan3_kernel(const int* __restrict__ loc,
                                                    const int* __restrict__ bsum,
                                                    int* __restrict__ rowptr,
                                                    int* __restrict__ cursor, int n, int nb) {
    int i = blockIdx.x * 256 + threadIdx.x;
    if (i < n) {
        int r = loc[i] + bsum[i >> 8];
        rowptr[i] = r;
        cursor[i] = r;
    }
    if (i == n) rowptr[n] = bsum[nb];
}

__global__ void scatter_kernel(const int* __restrict__ ei, int* __restrict__ cursor,
                               int* __restrict__ col, int E) {
    int e = blockIdx.x * blockDim.x + threadIdx.x;
    if (e >= E) return;
    int s = ei[e];
    int d = ei[E + e];
    int pos = atomicAdd(&cursor[d], 1);
    col[pos] = s;
}

// ---------- per-node scale vectors from out-degree ----------
// alpha: x -> yhat0 scale; beta = -2/deg; gam = 1/alpha (GEMM un-scale)
__global__ __launch_bounds__(256) void scaleprep_kernel(const int* __restrict__ deg_i,
                                                        float* __restrict__ beta,
                                                        float* __restrict__ alpha,
                                                        float* __restrict__ gam, int n) {
    int i = blockIdx.x * 256 + threadIdx.x;
    if (i >= n) return;
    int dg = deg_i[i];
    if (dg > 0) {
        float fd = (float)dg;
        beta[i] = -2.f / fd;
        alpha[i] = rsqrtf(fd);
        gam[i] = sqrtf(fd);
    } else {
        beta[i] = 0.f;
        alpha[i] = 1.f;
        gam[i] = 1.f;
    }
}

// ---------- x -> yhat_0 = alpha * x (fp16) ----------
__global__ __launch_bounds__(256) void cvt_kernel(const float* __restrict__ in,
                                                  const float* __restrict__ alpha,
                                                  ushort* __restrict__ out, int n8) {
    int i = blockIdx.x * 256 + threadIdx.x;
    if (i >= n8) return;
    int row = i >> 4;
    float al = alpha[row];
    float4 a = ((const float4*)in)[2 * i];
    float4 b = ((const float4*)in)[2 * i + 1];
    U4H8 p;
    p.h2[0] = __float22half2_rn(make_float2(al * a.x, al * a.y));
    p.h2[1] = __float22half2_rn(make_float2(al * a.z, al * a.w));
    p.h2[2] = __float22half2_rn(make_float2(al * b.x, al * b.y));
    p.h2[3] = __float22half2_rn(make_float2(al * b.z, al * b.w));
    ((uint4*)out)[i] = p.u;
}

// ---------- W prep: WT[k][n][c] = fp16(W[k][c][n]) ----------
__global__ __launch_bounds__(256) void wprep_kernel(const float* __restrict__ W,
                                                    ushort* __restrict__ WT) {
    int idx = blockIdx.x * 256 + threadIdx.x;   // (k, n, c4)
    if (idx >= K_ORD * 128 * 32) return;
    int c4 = idx & 31;
    int nrow = (idx >> 5) & 127;
    int k = idx >> 12;
    const float* Wk = W + (size_t)k * CH * CH;
    ushort o[4];
    #pragma unroll
    for (int j = 0; j < 4; ++j)
        o[j] = __half_as_ushort(__float2half_rn(Wk[(c4 * 4 + j) * CH + nrow]));
    *(ushort2*)(WT + (size_t)k * CH * CH + nrow * CH + c4 * 4)     = make_ushort2(o[0], o[1]);
    *(ushort2*)(WT + (size_t)k * CH * CH + nrow * CH + c4 * 4 + 2) = make_ushort2(o[2], o[3]);
}

// ---------- prop (yhat-space): unweighted gather, per-dst beta at write ----------
// yhat_k[i] = (mode ? beta[i]*G - yprev[i] : 0.5*beta[i]*G), G = sum yhat_{k-1}[src]
// one wave per node; 4 groups x 16 lanes; 16-edge unrolled blocks -> MLP=4/lane
__global__ __launch_bounds__(256) void prop_kernel(
    const ushort* __restrict__ tin, const ushort* __restrict__ tprev,
    ushort* __restrict__ tout, const int* __restrict__ rowptr,
    const int* __restrict__ col, const float* __restrict__ beta, int n, int mode) {
    int wid = blockIdx.x * 4 + (threadIdx.x >> 6);
    if (wid >= n) return;
    int lane = threadIdx.x & 63;
    int g = lane >> 4, sub = lane & 15;
    int beg = rowptr[wid], end = rowptr[wid + 1];
    float acc[8] = {0.f, 0.f, 0.f, 0.f, 0.f, 0.f, 0.f, 0.f};
    for (int e0 = beg; e0 < end; e0 += 64) {
        int ne = min(64, end - e0);
        int c = 0;
        if (lane < ne) c = col[e0 + lane];
        for (int j16 = 0; j16 < ne; j16 += 16) {
            U4H8 v[4];
            float m[4];
            #pragma unroll
            for (int u = 0; u < 4; ++u) {
                int j = j16 + u * 4 + g;
                int cj = __shfl(c, j & 63);
                m[u] = (j < ne) ? 1.f : 0.f;
                v[u].u = ((const uint4*)(tin + (size_t)cj * CH))[sub];
            }
            #pragma unroll
            for (int u = 0; u < 4; ++u) {
                #pragma unroll
                for (int t = 0; t < 4; ++t) {
                    float2 f = __half22float2(v[u].h2[t]);
                    acc[2 * t]     = fmaf(m[u], f.x, acc[2 * t]);
                    acc[2 * t + 1] = fmaf(m[u], f.y, acc[2 * t + 1]);
                }
            }
        }
    }
    #pragma unroll
    for (int i = 0; i < 8; ++i) {
        acc[i] += __shfl_xor(acc[i], 16);
        acc[i] += __shfl_xor(acc[i], 32);
    }
    if (g == 0) {
        float bt = beta[wid];
        size_t base = (size_t)wid * CH + sub * 8;
        float r[8];
        if (mode) {
            U4H8 pv;
            pv.u = *(const uint4*)(tprev + base);
            #pragma unroll
            for (int t = 0; t < 4; ++t) {
                float2 f = __half22float2(pv.h2[t]);
                r[2 * t]     = fmaf(bt, acc[2 * t],     -f.x);
                r[2 * t + 1] = fmaf(bt, acc[2 * t + 1], -f.y);
            }
        } else {
            float hb = 0.5f * bt;
            #pragma unroll
            for (int i = 0; i < 8; ++i) r[i] = hb * acc[i];
        }
        U4H8 p;
        p.h2[0] = __float22half2_rn(make_float2(r[0], r[1]));
        p.h2[1] = __float22half2_rn(make_float2(r[2], r[3]));
        p.h2[2] = __float22half2_rn(make_float2(r[4], r[5]));
        p.h2[3] = __float22half2_rn(make_float2(r[6], r[7]));
        *(uint4*)(tout + base) = p.u;
    }
}

// ---------- GEMM: C[M,128] (betaf? +=) Σ_ks (gam ⊙ Yhat[wk0+ks]) @ WT[wk0+ks] ----------
__global__ __launch_bounds__(256) void gemm_kernel(
    const ushort* __restrict__ T, size_t kstride, const ushort* __restrict__ WT,
    const float* __restrict__ gam, float* __restrict__ C,
    int M, int wk0, int nk, int betaf) {
    __shared__ ushort As[128 * 128];
    __shared__ ushort Ws[128 * 128];
    int tid = threadIdx.x;
    int row0 = blockIdx.x * 128;
    int wave = tid >> 6, lane = tid & 63;
    int wrow = wave * 32;
    int lr = lane & 15, kg = lane >> 4;

    f32x4 acc[2][8];
    #pragma unroll
    for (int a = 0; a < 2; ++a)
        #pragma unroll
        for (int c = 0; c < 8; ++c)
            acc[a][c] = (f32x4){0.f, 0.f, 0.f, 0.f};

    for (int ks = 0; ks < nk; ++ks) {
        const ushort* Ak = T + (size_t)ks * kstride;
        const ushort* Wk = WT + (size_t)(wk0 + ks) * (CH * CH);
        #pragma unroll
        for (int i = 0; i < 8; ++i) {
            int idx = tid + i * 256;
            int r = idx >> 4, gg = idx & 15;
            int gr = row0 + r;
            U4H8 hv;
            hv.u = make_uint4(0u, 0u, 0u, 0u);
            if (gr < M) {
                hv.u = ((const uint4*)(Ak + (size_t)gr * CH))[gg];
                float gm = gam[gr];
                #pragma unroll
                for (int t = 0; t < 4; ++t) {
                    float2 f = __half22float2(hv.h2[t]);
                    hv.h2[t] = __float22half2_rn(make_float2(gm * f.x, gm * f.y));
                }
            }
            int gs = gg ^ (r & 15);
            *(uint4*)(&As[r * 128 + gs * 8]) = hv.u;
        }
        #pragma unroll
        for (int i = 0; i < 8; ++i) {
            int idx = tid + i * 256;
            int r = idx >> 4, gg = idx & 15;
            uint4 v = ((const uint4*)(Wk + (size_t)r * CH))[gg];
            int gs = gg ^ (r & 15);
            *(uint4*)(&Ws[r * 128 + gs * 8]) = v;
        }
        __syncthreads();

        #pragma unroll
        for (int kc = 0; kc < 4; ++kc) {
            int gbase = kc * 4 + kg;
            int gs = gbase ^ lr;
            s16x8 a0 = *(const s16x8*)(&As[(wrow + lr) * 128 + gs * 8]);
            s16x8 a1 = *(const s16x8*)(&As[(wrow + 16 + lr) * 128 + gs * 8]);
            #pragma unroll
            for (int c = 0; c < 8; ++c) {
                s16x8 bfr = *(const s16x8*)(&Ws[(c * 16 + lr) * 128 + gs * 8]);
                acc[0][c] = __builtin_amdgcn_mfma_f32_16x16x32_f16(a0, bfr, acc[0][c], 0, 0, 0);
                acc[1][c] = __builtin_amdgcn_mfma_f32_16x16x32_f16(a1, bfr, acc[1][c], 0, 0, 0);
            }
        }
        __syncthreads();
    }

    #pragma unroll
    for (int rf = 0; rf < 2; ++rf)
        #pragma unroll
        for (int c = 0; c < 8; ++c)
            #pragma unroll
            for (int j = 0; j < 4; ++j) {
                int gr = row0 + wrow + rf * 16 + kg * 4 + j;
                int gc = c * 16 + lr;
                if (gr < M) {
                    float v = acc[rf][c][j];
                    if (betaf) v += C[(size_t)gr * 128 + gc];
                    C[(size_t)gr * 128 + gc] = v;
                }
            }
}

// ---------- head: MFMA over Wcat = [w_mu | w_ls], fused leaky+bias+normalize ----------
__global__ __launch_bounds__(256) void head_kernel(
    const float* __restrict__ acc_in, const float* __restrict__ b,
    const float* __restrict__ w_mu, const float* __restrict__ b_mu,
    const float* __restrict__ w_ls, const float* __restrict__ b_ls,
    float* __restrict__ out, int M) {
    __shared__ ushort Hs[128 * 128];
    __shared__ ushort Ws[128 * 128];
    __shared__ float s_b[128];
    int tid = threadIdx.x;
    int row0 = blockIdx.x * 128;
    if (tid < 128) s_b[tid] = b[tid];
    __syncthreads();

    #pragma unroll
    for (int i = 0; i < 16; ++i) {
        int idx = tid + i * 256;
        int r = idx >> 5, c4 = idx & 31;
        float4 v = make_float4(0.f, 0.f, 0.f, 0.f);
        int gr = row0 + r;
        if (gr < M) v = ((const float4*)(acc_in + (size_t)gr * CH))[c4];
        float hv[4] = { v.x, v.y, v.z, v.w };
        #pragma unroll
        for (int j = 0; j < 4; ++j) {
            float h = hv[j] + s_b[c4 * 4 + j];
            hv[j] = h > 0.f ? h : 0.01f * h;
        }
        __half2 p0 = __float22half2_rn(make_float2(hv[0], hv[1]));
        __half2 p1 = __float22half2_rn(make_float2(hv[2], hv[3]));
        int gg = c4 >> 1, hh = c4 & 1;
        int gs = gg ^ (r & 15);
        uint2 pk;
        pk.x = *(unsigned int*)&p0;
        pk.y = *(unsigned int*)&p1;
        *(uint2*)(&Hs[r * 128 + gs * 8 + hh * 4]) = pk;
    }
    #pragma unroll
    for (int i = 0; i < 16; ++i) {
        int idx = tid + i * 256;
        int k = idx >> 5, n4 = idx & 31;
        const float* src = (n4 < 16) ? w_mu : w_ls;
        float4 v = ((const float4*)src)[k * 16 + (n4 & 15)];
        int gk = k >> 3, kk = k & 7;
        float vv[4] = { v.x, v.y, v.z, v.w };
        #pragma unroll
        for (int j = 0; j < 4; ++j) {
            int nn = n4 * 4 + j;
            int gs = gk ^ (nn & 15);
            Ws[nn * 128 + gs * 8 + kk] = __half_as_ushort(__float2half_rn(vv[j]));
        }
    }
    __syncthreads();

    int wave = tid >> 6, lane = tid & 63;
    int wrow = wave * 32;
    int lr = lane & 15, kg = lane >> 4;
    f32x4 acc[2][8];
    #pragma unroll
    for (int a = 0; a < 2; ++a)
        #pragma unroll
        for (int c = 0; c < 8; ++c)
            acc[a][c] = (f32x4){0.f, 0.f, 0.f, 0.f};

    #pragma unroll
    for (int kc = 0; kc < 4; ++kc) {
        int gbase = kc * 4 + kg;
        int gs = gbase ^ lr;
        s16x8 a0 = *(const s16x8*)(&Hs[(wrow + lr) * 128 + gs * 8]);
        s16x8 a1 = *(const s16x8*)(&Hs[(wrow + 16 + lr) * 128 + gs * 8]);
        #pragma unroll
        for (int c = 0; c < 8; ++c) {
            s16x8 bfr = *(const s16x8*)(&Ws[(c * 16 + lr) * 128 + gs * 8]);
            acc[0][c] = __builtin_amdgcn_mfma_f32_16x16x32_f16(a0, bfr, acc[0][c], 0, 0, 0);
            acc[1][c] = __builtin_amdgcn_mfma_f32_16x16x32_f16(a1, bfr, acc[1][c], 0, 0, 0);
        }
    }

    #pragma unroll
    for (int rf = 0; rf < 2; ++rf)
        #pragma unroll
        for (int j = 0; j < 4; ++j) {
            int gr = row0 + wrow + rf * 16 + kg * 4 + j;
            float muv[4], lsv[4];
            float s2 = 0.f;
            #pragma unroll
            for (int c = 0; c < 4; ++c) {
                muv[c] = acc[rf][c][j] + b_mu[c * 16 + lr];
                float l = acc[rf][4 + c][j] + b_ls[c * 16 + lr];
                lsv[c] = l;
                s2 = fmaf(l, l, s2);
            }
            s2 += __shfl_xor(s2, 1);
            s2 += __shfl_xor(s2, 2);
            s2 += __shfl_xor(s2, 4);
            s2 += __shfl_xor(s2, 8);
            float sc = 1.8f / fmaxf(sqrtf(s2), 1e-12f);
            if (gr < M) {
                size_t base = (size_t)gr * OUT_CH;
                #pragma unroll
                for (int c = 0; c < 4; ++c) {
                    int gc = c * 16 + lr;
                    out[base + gc] = muv[c];
                    out[(size_t)N_NODES * OUT_CH + base + gc] = lsv[c] * sc;
                    out[2 * (size_t)N_NODES * OUT_CH + base + gc] = muv[c];
                }
            }
        }
}

// ---------- host ----------
extern "C" void kernel_launch(void* const* d_in, const int* in_sizes, int n_in,
                              void* d_out, int out_size, void* d_ws, size_t ws_size,
                              hipStream_t stream) {
    const float* x    = (const float*)d_in[0];
    const int*   ei   = (const int*)d_in[1];
    const float* W    = (const float*)d_in[2];
    const float* b    = (const float*)d_in[3];
    const float* w_mu = (const float*)d_in[4];
    const float* b_mu = (const float*)d_in[5];
    const float* w_ls = (const float*)d_in[6];
    const float* b_ls = (const float*)d_in[7];

    const int N = N_NODES, E = N_EDGES;
    const int NB = (N + 255) / 256;
    char* p = (char*)d_ws;
    auto alloc = [&](size_t bytes) {
        char* r = p;
        p += (bytes + 511) & ~(size_t)511;
        return r;
    };
    int*    deg_i  = (int*)alloc((size_t)N * 4);
    int*    indeg  = (int*)alloc((size_t)N * 4);
    int*    rowptr = (int*)alloc((size_t)(N + 1) * 4);
    int*    cursor = (int*)alloc((size_t)N * 4);
    int*    loc    = (int*)alloc((size_t)N * 4);
    int*    bsum   = (int*)alloc((size_t)(NB + 1) * 4);
    int*    col    = (int*)alloc((size_t)E * 4);
    float*  beta   = (float*)alloc((size_t)N * 4);
    float*  alpha  = (float*)alloc((size_t)N * 4);
    float*  gam    = (float*)alloc((size_t)N * 4);
    ushort* WT     = (ushort*)alloc((size_t)K_ORD * CH * CH * 2);
    float*  accbuf = (float*)alloc((size_t)N * CH * 4);

    size_t used = (size_t)(p - (char*)d_ws);
    bool bigpath = ws_size >= used + (size_t)K_ORD * SLICE * 2 + (1u << 20);

    (void)hipMemsetAsync(deg_i, 0, (size_t)N * 4, stream);
    (void)hipMemsetAsync(indeg, 0, (size_t)N * 4, stream);

    count_kernel<<<(E + 255) / 256, 256, 0, stream>>>(ei, deg_i, indeg, E);
    scan1_kernel<<<NB, 256, 0, stream>>>(indeg, loc, bsum, N);
    scan2_kernel<<<1, 256, 0, stream>>>(bsum, NB);
    scan3_kernel<<<NB, 256, 0, stream>>>(loc, bsum, rowptr, cursor, N, NB);
    scatter_kernel<<<(E + 255) / 256, 256, 0, stream>>>(ei, cursor, col, E);
    scaleprep_kernel<<<(N + 255) / 256, 256, 0, stream>>>(deg_i, beta, alpha, gam, N);
    wprep_kernel<<<(K_ORD * 128 * 32 + 255) / 256, 256, 0, stream>>>(W, WT);

    int gemm_grid = (N + 127) / 128;
    int prop_grid = (N + 3) / 4;
    int cvt_grid = (N * 16 + 255) / 256;

    if (bigpath) {
        ushort* T = (ushort*)alloc((size_t)K_ORD * SLICE * 2);  // yhat slices fp16
        // yhat_0 = alpha * x
        cvt_kernel<<<cvt_grid, 256, 0, stream>>>(x, alpha, T, N * 16);
        // yhat_1 = 0.5*beta*G(yhat_0)
        prop_kernel<<<prop_grid, 256, 0, stream>>>(T, T, T + SLICE,
                                                   rowptr, col, beta, N, 0);
        // yhat_k = beta*G(yhat_{k-1}) - yhat_{k-2}
        for (int k = 2; k < K_ORD; ++k)
            prop_kernel<<<prop_grid, 256, 0, stream>>>(
                T + (size_t)(k - 1) * SLICE, T + (size_t)(k - 2) * SLICE,
                T + (size_t)k * SLICE, rowptr, col, beta, N, 1);
        // acc = sum_k (gam ⊙ yhat_k) @ W_k  (single K=3200 GEMM)
        gemm_kernel<<<gemm_grid, 256, 0, stream>>>(T, SLICE, WT, gam, accbuf,
                                                   N, 0, K_ORD, 0);
    } else {
        ushort* r0 = (ushort*)alloc(SLICE * 2);
        ushort* r1 = (ushort*)alloc(SLICE * 2);
        ushort* r2 = (ushort*)alloc(SLICE * 2);
        ushort* Ss[3] = { r0, r1, r2 };
        cvt_kernel<<<cvt_grid, 256, 0, stream>>>(x, alpha, r0, N * 16);
        gemm_kernel<<<gemm_grid, 256, 0, stream>>>(r0, 0, WT, gam, accbuf, N, 0, 1, 0);
        prop_kernel<<<prop_grid, 256, 0, stream>>>(r0, r0, r1, rowptr, col, beta, N, 0);
        gemm_kernel<<<gemm_grid, 256, 0, stream>>>(r1, 0, WT, gam, accbuf, N, 1, 1, 1);
        for (int k = 2; k < K_ORD; ++k) {
            prop_kernel<<<prop_grid, 256, 0, stream>>>(
                Ss[(k - 1) % 3], Ss[(k - 2) % 3], Ss[k % 3], rowptr, col, beta, N, 1);
            gemm_kernel<<<gemm_grid, 256, 0, stream>>>(Ss[k % 3], 0, WT, gam, accbuf,
                                                       N, k, 1, 1);
        }
    }

    head_kernel<<<gemm_grid, 256, 0, stream>>>(accbuf, b, w_mu, b_mu, w_ls, b_ls,
                                               (float*)d_out, N);
}

// Round 11
// 1506.273 us; speedup vs baseline: 1.0065x; 1.0065x over previous
//
#include <hip/hip_runtime.h>
#include <hip/hip_fp16.h>

#define N_NODES 50000
#define N_EDGES 800000
#define CH 128
#define OUT_CH 64
#define K_ORD 25
#define SLICE ((size_t)N_NODES * CH)   // elements per T_k slice
#define NCOPY 8                        // XCD-private counter copies

typedef __attribute__((ext_vector_type(8))) short s16x8;
typedef __attribute__((ext_vector_type(4))) float f32x4;

union U4H8 { uint4 u; __half2 h2[4]; ushort us[8]; };

// ---------- CSR build with XCD-private atomics ----------
// copy = blockIdx.x & 7 ~ XCD id under round-robin dispatch; atomics stay XCD-local.
__global__ void count_kernel(const int* __restrict__ ei, int* __restrict__ deg8,
                             int* __restrict__ indeg8, int E, int n) {
    int e = blockIdx.x * blockDim.x + threadIdx.x;
    if (e >= E) return;
    int cp = blockIdx.x & (NCOPY - 1);
    int s = ei[e];
    int d = ei[E + e];
    atomicAdd(&deg8[cp * n + s], 1);
    atomicAdd(&indeg8[cp * n + d], 1);
}

__global__ __launch_bounds__(256) void fold_kernel(const int* __restrict__ indeg8,
                                                   int* __restrict__ indegN, int n) {
    int i = blockIdx.x * 256 + threadIdx.x;
    if (i >= n) return;
    int s = 0;
    #pragma unroll
    for (int c = 0; c < NCOPY; ++c) s += indeg8[c * n + i];
    indegN[i] = s;
}

__global__ __launch_bounds__(256) void scan1_kernel(const int* __restrict__ indeg,
                                                    int* __restrict__ loc,
                                                    int* __restrict__ bsum, int n) {
    __shared__ int tmp[256];
    int tid = threadIdx.x;
    int i = blockIdx.x * 256 + tid;
    int v = (i < n) ? indeg[i] : 0;
    tmp[tid] = v;
    __syncthreads();
    for (int off = 1; off < 256; off <<= 1) {
        int t = (tid >= off) ? tmp[tid - off] : 0;
        __syncthreads();
        tmp[tid] += t;
        __syncthreads();
    }
    if (i < n) loc[i] = tmp[tid] - v;
    if (tid == 255) bsum[blockIdx.x] = tmp[255];
}

__global__ __launch_bounds__(256) void scan2_kernel(int* __restrict__ bsum, int nb) {
    __shared__ int tmp[256];
    int tid = threadIdx.x;
    int v = (tid < nb) ? bsum[tid] : 0;
    tmp[tid] = v;
    __syncthreads();
    for (int off = 1; off < 256; off <<= 1) {
        int t = (tid >= off) ? tmp[tid - off] : 0;
        __syncthreads();
        tmp[tid] += t;
        __syncthreads();
    }
    if (tid < nb) bsum[tid] = tmp[tid] - v;
    if (tid == 255) bsum[nb] = tmp[255];
}

__global__ __launch_bounds__(256) void scan3_kernel(const int* __restrict__ loc,
                                                    const int* __restrict__ bsum,
                                                    int* __restrict__ rowptr, int n, int nb) {
    int i = blockIdx.x * 256 + threadIdx.x;
    if (i < n) rowptr[i] = loc[i] + bsum[i >> 8];
    if (i == n) rowptr[n] = bsum[nb];
}

// cursor8[c][node] = rowptr[node] + sum_{c'<c} indeg8[c'][node]
__global__ __launch_bounds__(256) void cursorinit_kernel(const int* __restrict__ rowptr,
                                                         const int* __restrict__ indeg8,
                                                         int* __restrict__ cursor8, int n) {
    int i = blockIdx.x * 256 + threadIdx.x;
    if (i >= n) return;
    int base = rowptr[i];
    #pragma unroll
    for (int c = 0; c < NCOPY; ++c) {
        cursor8[c * n + i] = base;
        base += indeg8[c * n + i];
    }
}

__global__ void scatter_kernel(const int* __restrict__ ei, int* __restrict__ cursor8,
                               int* __restrict__ col, int E, int n) {
    int e = blockIdx.x * blockDim.x + threadIdx.x;
    if (e >= E) return;
    int cp = blockIdx.x & (NCOPY - 1);
    int s = ei[e];
    int d = ei[E + e];
    int pos = atomicAdd(&cursor8[cp * n + d], 1);
    col[pos] = s;
}

// ---------- per-node scale vectors from out-degree (folds deg8) ----------
__global__ __launch_bounds__(256) void scaleprep_kernel(const int* __restrict__ deg8,
                                                        float* __restrict__ beta,
                                                        float* __restrict__ alpha,
                                                        float* __restrict__ gam, int n) {
    int i = blockIdx.x * 256 + threadIdx.x;
    if (i >= n) return;
    int dg = 0;
    #pragma unroll
    for (int c = 0; c < NCOPY; ++c) dg += deg8[c * n + i];
    if (dg > 0) {
        float fd = (float)dg;
        beta[i] = -2.f / fd;
        alpha[i] = rsqrtf(fd);
        gam[i] = sqrtf(fd);
    } else {
        beta[i] = 0.f;
        alpha[i] = 1.f;
        gam[i] = 1.f;
    }
}

// ---------- x -> yhat_0 = alpha * x (fp16) ----------
__global__ __launch_bounds__(256) void cvt_kernel(const float* __restrict__ in,
                                                  const float* __restrict__ alpha,
                                                  ushort* __restrict__ out, int n8) {
    int i = blockIdx.x * 256 + threadIdx.x;
    if (i >= n8) return;
    int row = i >> 4;
    float al = alpha[row];
    float4 a = ((const float4*)in)[2 * i];
    float4 b = ((const float4*)in)[2 * i + 1];
    U4H8 p;
    p.h2[0] = __float22half2_rn(make_float2(al * a.x, al * a.y));
    p.h2[1] = __float22half2_rn(make_float2(al * a.z, al * a.w));
    p.h2[2] = __float22half2_rn(make_float2(al * b.x, al * b.y));
    p.h2[3] = __float22half2_rn(make_float2(al * b.z, al * b.w));
    ((uint4*)out)[i] = p.u;
}

// ---------- W prep: WT[k][n][c] = fp16(W[k][c][n]) ----------
__global__ __launch_bounds__(256) void wprep_kernel(const float* __restrict__ W,
                                                    ushort* __restrict__ WT) {
    int idx = blockIdx.x * 256 + threadIdx.x;   // (k, n, c4)
    if (idx >= K_ORD * 128 * 32) return;
    int c4 = idx & 31;
    int nrow = (idx >> 5) & 127;
    int k = idx >> 12;
    const float* Wk = W + (size_t)k * CH * CH;
    ushort o[4];
    #pragma unroll
    for (int j = 0; j < 4; ++j)
        o[j] = __half_as_ushort(__float2half_rn(Wk[(c4 * 4 + j) * CH + nrow]));
    *(ushort2*)(WT + (size_t)k * CH * CH + nrow * CH + c4 * 4)     = make_ushort2(o[0], o[1]);
    *(ushort2*)(WT + (size_t)k * CH * CH + nrow * CH + c4 * 4 + 2) = make_ushort2(o[2], o[3]);
}

// ---------- prop (yhat-space): unweighted gather, per-dst beta at write ----------
__global__ __launch_bounds__(256) void prop_kernel(
    const ushort* __restrict__ tin, const ushort* __restrict__ tprev,
    ushort* __restrict__ tout, const int* __restrict__ rowptr,
    const int* __restrict__ col, const float* __restrict__ beta, int n, int mode) {
    int wid = blockIdx.x * 4 + (threadIdx.x >> 6);
    if (wid >= n) return;
    int lane = threadIdx.x & 63;
    int g = lane >> 4, sub = lane & 15;
    int beg = rowptr[wid], end = rowptr[wid + 1];
    float acc[8] = {0.f, 0.f, 0.f, 0.f, 0.f, 0.f, 0.f, 0.f};
    for (int e0 = beg; e0 < end; e0 += 64) {
        int ne = min(64, end - e0);
        int c = 0;
        if (lane < ne) c = col[e0 + lane];
        for (int j16 = 0; j16 < ne; j16 += 16) {
            U4H8 v[4];
            float m[4];
            #pragma unroll
            for (int u = 0; u < 4; ++u) {
                int j = j16 + u * 4 + g;
                int cj = __shfl(c, j & 63);
                m[u] = (j < ne) ? 1.f : 0.f;
                v[u].u = ((const uint4*)(tin + (size_t)cj * CH))[sub];
            }
            #pragma unroll
            for (int u = 0; u < 4; ++u) {
                #pragma unroll
                for (int t = 0; t < 4; ++t) {
                    float2 f = __half22float2(v[u].h2[t]);
                    acc[2 * t]     = fmaf(m[u], f.x, acc[2 * t]);
                    acc[2 * t + 1] = fmaf(m[u], f.y, acc[2 * t + 1]);
                }
            }
        }
    }
    #pragma unroll
    for (int i = 0; i < 8; ++i) {
        acc[i] += __shfl_xor(acc[i], 16);
        acc[i] += __shfl_xor(acc[i], 32);
    }
    if (g == 0) {
        float bt = beta[wid];
        size_t base = (size_t)wid * CH + sub * 8;
        float r[8];
        if (mode) {
            U4H8 pv;
            pv.u = *(const uint4*)(tprev + base);
            #pragma unroll
            for (int t = 0; t < 4; ++t) {
                float2 f = __half22float2(pv.h2[t]);
                r[2 * t]     = fmaf(bt, acc[2 * t],     -f.x);
                r[2 * t + 1] = fmaf(bt, acc[2 * t + 1], -f.y);
            }
        } else {
            float hb = 0.5f * bt;
            #pragma unroll
            for (int i = 0; i < 8; ++i) r[i] = hb * acc[i];
        }
        U4H8 p;
        p.h2[0] = __float22half2_rn(make_float2(r[0], r[1]));
        p.h2[1] = __float22half2_rn(make_float2(r[2], r[3]));
        p.h2[2] = __float22half2_rn(make_float2(r[4], r[5]));
        p.h2[3] = __float22half2_rn(make_float2(r[6], r[7]));
        *(uint4*)(tout + base) = p.u;
    }
}

// ---------- GEMM: blockIdx.y picks (wk0,nk,C); C = Σ_ks (gam ⊙ Yhat) @ WT ----------
__global__ __launch_bounds__(256) void gemm_kernel(
    const ushort* __restrict__ T, size_t kstride, const ushort* __restrict__ WT,
    const float* __restrict__ gam, float* __restrict__ C0, float* __restrict__ C1,
    int M, int k0a, int nka, int k0b, int nkb, int betaf) {
    int wk0 = (blockIdx.y == 0) ? k0a : k0b;
    int nk  = (blockIdx.y == 0) ? nka : nkb;
    float* C = (blockIdx.y == 0) ? C0 : C1;
    __shared__ ushort As[128 * 128];
    __shared__ ushort Ws[128 * 128];
    int tid = threadIdx.x;
    int row0 = blockIdx.x * 128;
    int wave = tid >> 6, lane = tid & 63;
    int wrow = wave * 32;
    int lr = lane & 15, kg = lane >> 4;

    f32x4 acc[2][8];
    #pragma unroll
    for (int a = 0; a < 2; ++a)
        #pragma unroll
        for (int c = 0; c < 8; ++c)
            acc[a][c] = (f32x4){0.f, 0.f, 0.f, 0.f};

    for (int ks = 0; ks < nk; ++ks) {
        const ushort* Ak = T + (size_t)(wk0 + ks) * kstride;
        const ushort* Wk = WT + (size_t)(wk0 + ks) * (CH * CH);
        #pragma unroll
        for (int i = 0; i < 8; ++i) {
            int idx = tid + i * 256;
            int r = idx >> 4, gg = idx & 15;
            int gr = row0 + r;
            U4H8 hv;
            hv.u = make_uint4(0u, 0u, 0u, 0u);
            if (gr < M) {
                hv.u = ((const uint4*)(Ak + (size_t)gr * CH))[gg];
                float gm = gam[gr];
                #pragma unroll
                for (int t = 0; t < 4; ++t) {
                    float2 f = __half22float2(hv.h2[t]);
                    hv.h2[t] = __float22half2_rn(make_float2(gm * f.x, gm * f.y));
                }
            }
            int gs = gg ^ (r & 15);
            *(uint4*)(&As[r * 128 + gs * 8]) = hv.u;
        }
        #pragma unroll
        for (int i = 0; i < 8; ++i) {
            int idx = tid + i * 256;
            int r = idx >> 4, gg = idx & 15;
            uint4 v = ((const uint4*)(Wk + (size_t)r * CH))[gg];
            int gs = gg ^ (r & 15);
            *(uint4*)(&Ws[r * 128 + gs * 8]) = v;
        }
        __syncthreads();

        #pragma unroll
        for (int kc = 0; kc < 4; ++kc) {
            int gbase = kc * 4 + kg;
            int gs = gbase ^ lr;
            s16x8 a0 = *(const s16x8*)(&As[(wrow + lr) * 128 + gs * 8]);
            s16x8 a1 = *(const s16x8*)(&As[(wrow + 16 + lr) * 128 + gs * 8]);
            #pragma unroll
            for (int c = 0; c < 8; ++c) {
                s16x8 bfr = *(const s16x8*)(&Ws[(c * 16 + lr) * 128 + gs * 8]);
                acc[0][c] = __builtin_amdgcn_mfma_f32_16x16x32_f16(a0, bfr, acc[0][c], 0, 0, 0);
                acc[1][c] = __builtin_amdgcn_mfma_f32_16x16x32_f16(a1, bfr, acc[1][c], 0, 0, 0);
            }
        }
        __syncthreads();
    }

    #pragma unroll
    for (int rf = 0; rf < 2; ++rf)
        #pragma unroll
        for (int c = 0; c < 8; ++c)
            #pragma unroll
            for (int j = 0; j < 4; ++j) {
                int gr = row0 + wrow + rf * 16 + kg * 4 + j;
                int gc = c * 16 + lr;
                if (gr < M) {
                    float v = acc[rf][c][j];
                    if (betaf) v += C[(size_t)gr * 128 + gc];
                    C[(size_t)gr * 128 + gc] = v;
                }
            }
}

// ---------- head: h = leaky(acc0 (+acc1) + b); Wcat MFMA; normalize ----------
__global__ __launch_bounds__(256) void head_kernel(
    const float* __restrict__ acc0, const float* __restrict__ acc1, int use2,
    const float* __restrict__ b, const float* __restrict__ w_mu,
    const float* __restrict__ b_mu, const float* __restrict__ w_ls,
    const float* __restrict__ b_ls, float* __restrict__ out, int M) {
    __shared__ ushort Hs[128 * 128];
    __shared__ ushort Ws[128 * 128];
    __shared__ float s_b[128];
    int tid = threadIdx.x;
    int row0 = blockIdx.x * 128;
    if (tid < 128) s_b[tid] = b[tid];
    __syncthreads();

    #pragma unroll
    for (int i = 0; i < 16; ++i) {
        int idx = tid + i * 256;
        int r = idx >> 5, c4 = idx & 31;
        float4 v = make_float4(0.f, 0.f, 0.f, 0.f);
        int gr = row0 + r;
        if (gr < M) {
            v = ((const float4*)(acc0 + (size_t)gr * CH))[c4];
            if (use2) {
                float4 w = ((const float4*)(acc1 + (size_t)gr * CH))[c4];
                v.x += w.x; v.y += w.y; v.z += w.z; v.w += w.w;
            }
        }
        float hv[4] = { v.x, v.y, v.z, v.w };
        #pragma unroll
        for (int j = 0; j < 4; ++j) {
            float h = hv[j] + s_b[c4 * 4 + j];
            hv[j] = h > 0.f ? h : 0.01f * h;
        }
        __half2 p0 = __float22half2_rn(make_float2(hv[0], hv[1]));
        __half2 p1 = __float22half2_rn(make_float2(hv[2], hv[3]));
        int gg = c4 >> 1, hh = c4 & 1;
        int gs = gg ^ (r & 15);
        uint2 pk;
        pk.x = *(unsigned int*)&p0;
        pk.y = *(unsigned int*)&p1;
        *(uint2*)(&Hs[r * 128 + gs * 8 + hh * 4]) = pk;
    }
    #pragma unroll
    for (int i = 0; i < 16; ++i) {
        int idx = tid + i * 256;
        int k = idx >> 5, n4 = idx & 31;
        const float* src = (n4 < 16) ? w_mu : w_ls;
        float4 v = ((const float4*)src)[k * 16 + (n4 & 15)];
        int gk = k >> 3, kk = k & 7;
        float vv[4] = { v.x, v.y, v.z, v.w };
        #pragma unroll
        for (int j = 0; j < 4; ++j) {
            int nn = n4 * 4 + j;
            int gs = gk ^ (nn & 15);
            Ws[nn * 128 + gs * 8 + kk] = __half_as_ushort(__float2half_rn(vv[j]));
        }
    }
    __syncthreads();

    int wave = tid >> 6, lane = tid & 63;
    int wrow = wave * 32;
    int lr = lane & 15, kg = lane >> 4;
    f32x4 acc[2][8];
    #pragma unroll
    for (int a = 0; a < 2; ++a)
        #pragma unroll
        for (int c = 0; c < 8; ++c)
            acc[a][c] = (f32x4){0.f, 0.f, 0.f, 0.f};

    #pragma unroll
    for (int kc = 0; kc < 4; ++kc) {
        int gbase = kc * 4 + kg;
        int gs = gbase ^ lr;
        s16x8 a0 = *(const s16x8*)(&Hs[(wrow + lr) * 128 + gs * 8]);
        s16x8 a1 = *(const s16x8*)(&Hs[(wrow + 16 + lr) * 128 + gs * 8]);
        #pragma unroll
        for (int c = 0; c < 8; ++c) {
            s16x8 bfr = *(const s16x8*)(&Ws[(c * 16 + lr) * 128 + gs * 8]);
            acc[0][c] = __builtin_amdgcn_mfma_f32_16x16x32_f16(a0, bfr, acc[0][c], 0, 0, 0);
            acc[1][c] = __builtin_amdgcn_mfma_f32_16x16x32_f16(a1, bfr, acc[1][c], 0, 0, 0);
        }
    }

    #pragma unroll
    for (int rf = 0; rf < 2; ++rf)
        #pragma unroll
        for (int j = 0; j < 4; ++j) {
            int gr = row0 + wrow + rf * 16 + kg * 4 + j;
            float muv[4], lsv[4];
            float s2 = 0.f;
            #pragma unroll
            for (int c = 0; c < 4; ++c) {
                muv[c] = acc[rf][c][j] + b_mu[c * 16 + lr];
                float l = acc[rf][4 + c][j] + b_ls[c * 16 + lr];
                lsv[c] = l;
                s2 = fmaf(l, l, s2);
            }
            s2 += __shfl_xor(s2, 1);
            s2 += __shfl_xor(s2, 2);
            s2 += __shfl_xor(s2, 4);
            s2 += __shfl_xor(s2, 8);
            float sc = 1.8f / fmaxf(sqrtf(s2), 1e-12f);
            if (gr < M) {
                size_t base = (size_t)gr * OUT_CH;
                #pragma unroll
                for (int c = 0; c < 4; ++c) {
                    int gc = c * 16 + lr;
                    out[base + gc] = muv[c];
                    out[(size_t)N_NODES * OUT_CH + base + gc] = lsv[c] * sc;
                    out[2 * (size_t)N_NODES * OUT_CH + base + gc] = muv[c];
                }
            }
        }
}

// ---------- host ----------
extern "C" void kernel_launch(void* const* d_in, const int* in_sizes, int n_in,
                              void* d_out, int out_size, void* d_ws, size_t ws_size,
                              hipStream_t stream) {
    const float* x    = (const float*)d_in[0];
    const int*   ei   = (const int*)d_in[1];
    const float* W    = (const float*)d_in[2];
    const float* b    = (const float*)d_in[3];
    const float* w_mu = (const float*)d_in[4];
    const float* b_mu = (const float*)d_in[5];
    const float* w_ls = (const float*)d_in[6];
    const float* b_ls = (const float*)d_in[7];

    const int N = N_NODES, E = N_EDGES;
    const int NB = (N + 255) / 256;
    char* p = (char*)d_ws;
    auto alloc = [&](size_t bytes) {
        char* r = p;
        p += (bytes + 511) & ~(size_t)511;
        return r;
    };
    int*    deg8    = (int*)alloc((size_t)NCOPY * N * 4);
    int*    indeg8  = (int*)alloc((size_t)NCOPY * N * 4);
    int*    cursor8 = (int*)alloc((size_t)NCOPY * N * 4);
    int*    indegN  = (int*)alloc((size_t)N * 4);
    int*    rowptr  = (int*)alloc((size_t)(N + 1) * 4);
    int*    loc     = (int*)alloc((size_t)N * 4);
    int*    bsum    = (int*)alloc((size_t)(NB + 1) * 4);
    int*    col     = (int*)alloc((size_t)E * 4);
    float*  beta    = (float*)alloc((size_t)N * 4);
    float*  alpha   = (float*)alloc((size_t)N * 4);
    float*  gam     = (float*)alloc((size_t)N * 4);
    ushort* WT      = (ushort*)alloc((size_t)K_ORD * CH * CH * 2);
    float*  accbuf0 = (float*)alloc((size_t)N * CH * 4);
    float*  accbuf1 = (float*)alloc((size_t)N * CH * 4);

    size_t used = (size_t)(p - (char*)d_ws);
    bool bigpath = ws_size >= used + (size_t)K_ORD * SLICE * 2 + (1u << 20);

    (void)hipMemsetAsync(deg8, 0, (size_t)NCOPY * N * 4, stream);
    (void)hipMemsetAsync(indeg8, 0, (size_t)NCOPY * N * 4, stream);

    count_kernel<<<(E + 255) / 256, 256, 0, stream>>>(ei, deg8, indeg8, E, N);
    fold_kernel<<<NB, 256, 0, stream>>>(indeg8, indegN, N);
    scan1_kernel<<<NB, 256, 0, stream>>>(indegN, loc, bsum, N);
    scan2_kernel<<<1, 256, 0, stream>>>(bsum, NB);
    scan3_kernel<<<NB + 1, 256, 0, stream>>>(loc, bsum, rowptr, N, NB);
    cursorinit_kernel<<<NB, 256, 0, stream>>>(rowptr, indeg8, cursor8, N);
    scatter_kernel<<<(E + 255) / 256, 256, 0, stream>>>(ei, cursor8, col, E, N);
    scaleprep_kernel<<<NB, 256, 0, stream>>>(deg8, beta, alpha, gam, N);
    wprep_kernel<<<(K_ORD * 128 * 32 + 255) / 256, 256, 0, stream>>>(W, WT);

    int gemm_grid = (N + 127) / 128;
    int prop_grid = (N + 3) / 4;
    int cvt_grid = (N * 16 + 255) / 256;

    if (bigpath) {
        ushort* T = (ushort*)alloc((size_t)K_ORD * SLICE * 2);  // yhat slices fp16
        // yhat_0 = alpha * x
        cvt_kernel<<<cvt_grid, 256, 0, stream>>>(x, alpha, T, N * 16);
        // yhat_1 = 0.5*beta*G(yhat_0)
        prop_kernel<<<prop_grid, 256, 0, stream>>>(T, T, T + SLICE,
                                                   rowptr, col, beta, N, 0);
        // yhat_k = beta*G(yhat_{k-1}) - yhat_{k-2}
        for (int k = 2; k < K_ORD; ++k)
            prop_kernel<<<prop_grid, 256, 0, stream>>>(
                T + (size_t)(k - 1) * SLICE, T + (size_t)(k - 2) * SLICE,
                T + (size_t)k * SLICE, rowptr, col, beta, N, 1);
        // acc0 = Σ_{k<13}, acc1 = Σ_{k>=13}  (split-K over blockIdx.y)
        gemm_kernel<<<dim3(gemm_grid, 2), 256, 0, stream>>>(
            T, SLICE, WT, gam, accbuf0, accbuf1, N, 0, 13, 13, 12, 0);
        head_kernel<<<gemm_grid, 256, 0, stream>>>(accbuf0, accbuf1, 1, b,
                                                   w_mu, b_mu, w_ls, b_ls,
                                                   (float*)d_out, N);
    } else {
        ushort* r0 = (ushort*)alloc(SLICE * 2);
        ushort* r1 = (ushort*)alloc(SLICE * 2);
        ushort* r2 = (ushort*)alloc(SLICE * 2);
        ushort* Ss[3] = { r0, r1, r2 };
        cvt_kernel<<<cvt_grid, 256, 0, stream>>>(x, alpha, r0, N * 16);
        gemm_kernel<<<dim3(gemm_grid, 1), 256, 0, stream>>>(
            r0, 0, WT, gam, accbuf0, accbuf0, N, 0, 1, 0, 0, 0);
        prop_kernel<<<prop_grid, 256, 0, stream>>>(r0, r0, r1, rowptr, col, beta, N, 0);
        gemm_kernel<<<dim3(gemm_grid, 1), 256, 0, stream>>>(
            r1, 0, WT + (size_t)CH * CH, gam, accbuf0, accbuf0, N, 0, 1, 0, 0, 1);
        for (int k = 2; k < K_ORD; ++k) {
            prop_kernel<<<prop_grid, 256, 0, stream>>>(
                Ss[(k - 1) % 3], Ss[(k - 2) % 3], Ss[k % 3], rowptr, col, beta, N, 1);
            gemm_kernel<<<dim3(gemm_grid, 1), 256, 0, stream>>>(
                Ss[k % 3], 0, WT + (size_t)k * CH * CH, gam, accbuf0, accbuf0,
                N, 0, 1, 0, 0, 1);
        }
        head_kernel<<<gemm_grid, 256, 0, stream>>>(accbuf0, accbuf0, 0, b,
                                                   w_mu, b_mu, w_ls, b_ls,
                                                   (float*)d_out, N);
    }
}